// Round 1
// baseline (719.566 us; speedup 1.0000x reference)
//
#include <hip/hip_runtime.h>

#define Bz 8
#define Nn 2048
#define Cc 128
#define KK 16
#define WD 512
#define F2 64
#define FO 128
#define NP (Bz*Nn)
#define SQ2 1.41421356237309515f

// ws layout (float offsets)
#define GOFF   ((size_t)0)
#define BEOFF  ((size_t)1024)
#define LSOFF  ((size_t)2048)
#define HOFF   ((size_t)3072)
#define SQOFF  (HOFF + (size_t)NP*Cc)
#define A1OFF  (SQOFF + (size_t)NP)
#define ADOFF  (A1OFF + (size_t)NP*F2)
#define HXOFF  (ADOFF + (size_t)NP*Cc)
#define IXOFF  (HXOFF + (size_t)NP*Cc)

// ---------------------------------------------------------------------------
// Kernel 1: per-batch FiLM vectors  g = 1 + w@Wg, beta = w@Wb, ls = w@Wls+bls
__global__ __launch_bounds__(128) void k_pervec(const float* __restrict__ w,
    const float* __restrict__ Wg, const float* __restrict__ Wb,
    const float* __restrict__ Wls, const float* __restrict__ bls,
    float* __restrict__ ws) {
  const int b = blockIdx.x, c = threadIdx.x;
  const float* wr = w + b*WD;
  float ag = 0.f, ab = 0.f, al = 0.f;
  for (int d = 0; d < WD; ++d) {
    float wv = wr[d];                      // wave-uniform -> s_load
    ag = fmaf(wv, Wg[d*Cc + c], ag);
    ab = fmaf(wv, Wb[d*Cc + c], ab);
    al = fmaf(wv, Wls[d*Cc + c], al);
  }
  ws[GOFF  + b*Cc + c] = 1.0f + ag;
  ws[BEOFF + b*Cc + c] = ab;
  ws[LSOFF + b*Cc + c] = al + bls[c];
}

// ---------------------------------------------------------------------------
// Kernel 2: h = LN(x)*g + beta, sq = sum(h*h).  One wave per row.
__global__ __launch_bounds__(64) void k_h(const float* __restrict__ x,
                                          float* __restrict__ ws) {
  const int n = blockIdx.x;
  const int b = n >> 11;
  const int t = threadIdx.x;
  const float* xr = x + (size_t)n*Cc;
  float x0 = xr[t], x1 = xr[t + 64];
  float s = x0 + x1, ss = x0*x0 + x1*x1;
  #pragma unroll
  for (int m = 1; m < 64; m <<= 1) {
    s  += __shfl_xor(s,  m, 64);
    ss += __shfl_xor(ss, m, 64);
  }
  float mu  = s * (1.0f/128.0f);
  float var = ss * (1.0f/128.0f) - mu*mu;
  float rs  = rsqrtf(var + 1e-5f);
  float h0 = (x0 - mu)*rs*ws[GOFF + b*Cc + t]      + ws[BEOFF + b*Cc + t];
  float h1 = (x1 - mu)*rs*ws[GOFF + b*Cc + t + 64] + ws[BEOFF + b*Cc + t + 64];
  float* hr = ws + HOFF + (size_t)n*Cc;
  hr[t] = h0; hr[t + 64] = h1;
  float q = h0*h0 + h1*h1;
  #pragma unroll
  for (int m = 1; m < 64; m <<= 1) q += __shfl_xor(q, m, 64);
  if (t == 0) ws[SQOFF + n] = q;
}

// ---------------------------------------------------------------------------
// Kernel 3: precompute A1 = h@W1, Ad = h@Wx1[128:], hxb = h@Wx1[:128]-Ad+bx1
__global__ __launch_bounds__(128) void k_pre(const float* __restrict__ W1,
    const float* __restrict__ Wx1, const float* __restrict__ bx1,
    float* __restrict__ ws) {
  __shared__ float hs[4][Cc];
  const int t = threadIdx.x;
  const size_t row0 = (size_t)blockIdx.x * 4;
  const float* h = ws + HOFF;
  #pragma unroll
  for (int r = 0; r < 4; ++r) hs[r][t] = h[(row0 + r)*Cc + t];
  __syncthreads();
  float ad[4] = {0,0,0,0}, ac[4] = {0,0,0,0};
  for (int cp = 0; cp < Cc; ++cp) {
    float whi = Wx1[cp*FO + t];
    float wlo = Wx1[(Cc + cp)*FO + t];
    #pragma unroll
    for (int r = 0; r < 4; ++r) {
      float hv = hs[r][cp];
      ac[r] = fmaf(hv, whi, ac[r]);
      ad[r] = fmaf(hv, wlo, ad[r]);
    }
  }
  float bx = bx1[t];
  #pragma unroll
  for (int r = 0; r < 4; ++r) {
    ws[ADOFF + (row0 + r)*Cc + t] = ad[r];
    ws[HXOFF + (row0 + r)*Cc + t] = ac[r] - ad[r] + bx;
  }
  const int j = t & 63, rp = t >> 6;
  float a0 = 0.f, a1 = 0.f;
  for (int cp = 0; cp < Cc; ++cp) {
    float wv = W1[cp*F2 + j];
    a0 = fmaf(hs[rp][cp],     wv, a0);
    a1 = fmaf(hs[rp + 2][cp], wv, a1);
  }
  ws[A1OFF + (row0 + rp)*F2 + j]     = a0;
  ws[A1OFF + (row0 + rp + 2)*F2 + j] = a1;
}

// ---------------------------------------------------------------------------
// top-17 insert, fully unrolled cndmask form (arrays stay in VGPRs)
__device__ __forceinline__ void ins17(float d, int id, float (&td)[17],
                                      int (&ti)[17], float& cmax, int& cpos) {
  #pragma unroll
  for (int s = 0; s < 17; ++s) {
    bool r = (s == cpos);
    td[s] = r ? d  : td[s];
    ti[s] = r ? id : ti[s];
  }
  cmax = td[0]; cpos = 0;
  #pragma unroll
  for (int s = 1; s < 17; ++s)
    if (td[s] > cmax) { cmax = td[s]; cpos = s; }
}

// ---------------------------------------------------------------------------
// Kernel 4: fused pairwise distance + kNN(17) selection.
// Block: 256 thr, 64 n-rows; loop m in 64-tiles; dist = sqA+sqB-2*dot.
// Each thread owns (row i = t&63, quarter qd = t>>6) partial top-17; merged at end.
__global__ __launch_bounds__(256) void k_knn(float* __restrict__ ws) {
  __shared__ float hA[64][132];   // padded: conflict-free b128 reads
  __shared__ float hB[64][36];    // one 32-col c-chunk of the m-tile
  __shared__ float dS[64][68];
  __shared__ float sqA[64];
  __shared__ float sqB[64];
  const int t  = threadIdx.x;
  const int b  = blockIdx.x >> 5;
  const int i0 = (blockIdx.x & 31) << 6;
  const float* __restrict__ h  = ws + HOFF  + (size_t)b*Nn*Cc;
  const float* __restrict__ sq = ws + SQOFF + (size_t)b*Nn;

  { // load hA: 64x128, coalesced
    int r = t >> 2, cb = (t & 3) * 32;
    const float* src = h + (size_t)(i0 + r)*Cc + cb;
    #pragma unroll
    for (int q = 0; q < 8; ++q)
      *(float4*)(&hA[r][cb + q*4]) = *(const float4*)(src + q*4);
  }
  if (t < 64) sqA[t] = sq[i0 + t];

  const int tx = t & 15, ty = t >> 4;     // j-group, i-group
  const int iown = t & 63, qd = t >> 6;   // selection ownership

  float td[17]; int ti[17];
  #pragma unroll
  for (int s = 0; s < 17; ++s) { td[s] = 3.0e38f; ti[s] = -1; }
  float cmax = 3.0e38f; int cpos = 0;

  for (int j0 = 0; j0 < Nn; j0 += 64) {
    if (t < 64) sqB[t] = sq[j0 + t];
    float acc[4][4];
    #pragma unroll
    for (int a = 0; a < 4; ++a)
      #pragma unroll
      for (int d = 0; d < 4; ++d) acc[a][d] = 0.f;

    for (int cc = 0; cc < 4; ++cc) {
      __syncthreads();                       // fences prev select / hB reuse
      { // load hB chunk: 64 rows x 32 cols
        int r = t >> 2, cb = (t & 3) * 8;
        const float* src = h + (size_t)(j0 + r)*Cc + cc*32 + cb;
        *(float4*)(&hB[r][cb])     = *(const float4*)(src);
        *(float4*)(&hB[r][cb + 4]) = *(const float4*)(src + 4);
      }
      __syncthreads();
      #pragma unroll
      for (int q = 0; q < 8; ++q) {
        float4 av[4], bv[4];
        #pragma unroll
        for (int a = 0; a < 4; ++a)
          av[a] = *(const float4*)(&hA[ty + 16*a][cc*32 + q*4]);
        #pragma unroll
        for (int d = 0; d < 4; ++d)
          bv[d] = *(const float4*)(&hB[tx + 16*d][q*4]);
        #pragma unroll
        for (int a = 0; a < 4; ++a)
          #pragma unroll
          for (int d = 0; d < 4; ++d) {
            acc[a][d] = fmaf(av[a].x, bv[d].x, acc[a][d]);
            acc[a][d] = fmaf(av[a].y, bv[d].y, acc[a][d]);
            acc[a][d] = fmaf(av[a].z, bv[d].z, acc[a][d]);
            acc[a][d] = fmaf(av[a].w, bv[d].w, acc[a][d]);
          }
      }
    }
    // stage distances
    #pragma unroll
    for (int a = 0; a < 4; ++a)
      #pragma unroll
      for (int d = 0; d < 4; ++d)
        dS[ty + 16*a][tx + 16*d] =
            sqA[ty + 16*a] + sqB[tx + 16*d] - 2.f*acc[a][d];
    __syncthreads();
    // select: each thread scans its 16-col quarter of its row
    #pragma unroll 1
    for (int jj = 0; jj < 16; ++jj) {
      int j = qd*16 + jj;
      float dv = dS[iown][j];
      if (dv < cmax) ins17(dv, j0 + j, td, ti, cmax, cpos);
    }
  }
  __syncthreads();
  // dump 4 partial lists per row (ids bit-cast into hA, now dead)
  #pragma unroll
  for (int s = 0; s < 17; ++s) {
    dS[iown][qd*17 + s] = td[s];
    hA[iown][qd*17 + s] = __int_as_float(ti[s]);
  }
  __syncthreads();
  if (t < 64) {
    float md[17]; int mi[17];
    #pragma unroll
    for (int s = 0; s < 17; ++s) { md[s] = 3.0e38f; mi[s] = -1; }
    float cm = 3.0e38f; int cp = 0;
    for (int s = 0; s < 68; ++s) {
      float dv = dS[t][s];
      int  id = __float_as_int(hA[t][s]);
      if (dv < cm) ins17(dv, id, md, mi, cm, cp);
    }
    float mn = md[0]; int mp = 0;           // drop closest (= self)
    #pragma unroll
    for (int s = 1; s < 17; ++s) if (md[s] < mn) { mn = md[s]; mp = s; }
    int* op = (int*)(ws + IXOFF) + (size_t)(b*Nn + i0 + t)*KK;
    int kk = 0;
    #pragma unroll
    for (int s = 0; s < 17; ++s)
      if (s != mp) op[kk++] = b*Nn + mi[s];
  }
}

// ---------------------------------------------------------------------------
// Kernel 5: fused per-point MLP + softmax + aggregate + residual.
// One wave per point; thread owns channels {t, t+64}; k lives in registers.
// b2 omitted: constant over k -> cancels in softmax (exact).
__global__ __launch_bounds__(64) void k_mlp(
    const float* __restrict__ b1v, const float* __restrict__ W2,
    const float* __restrict__ Wx2, const float* __restrict__ bx2,
    const float* __restrict__ x, float* __restrict__ out,
    float* __restrict__ ws) {
  __shared__ float hw_s[64][20];   // [j][k], stride 20 -> aligned b128 rows
  __shared__ float hx_s[128][20];
  __shared__ int mk[16];
  const int n = blockIdx.x;
  const int b = n >> 11;
  const int t = threadIdx.x;
  const int* __restrict__ ip = (const int*)(ws + IXOFF) + (size_t)n*KK;
  if (t < 16) mk[t] = ip[t];
  __syncthreads();
  // phase A: hw[k][j] = lrelu(A1[m_k] - A1[n] + b1)
  {
    const float* A1 = ws + A1OFF;
    float a1n = A1[(size_t)n*F2 + t];
    float bb  = b1v[t];
    #pragma unroll
    for (int k = 0; k < 16; ++k) {
      float v = A1[(size_t)mk[k]*F2 + t] - a1n + bb;
      v = (v > 0.f ? v : 0.2f*v) * SQ2;
      hw_s[t][k] = v;
    }
  }
  __syncthreads();
  // phase B: wlog[k][c] = hw @ W2
  float wlA[16], wlB[16];
  #pragma unroll
  for (int k = 0; k < 16; ++k) { wlA[k] = 0.f; wlB[k] = 0.f; }
  for (int j = 0; j < 64; ++j) {
    float w2a = W2[j*FO + t];
    float w2b = W2[j*FO + t + 64];
    const float4* hp = (const float4*)(&hw_s[j][0]);
    float4 q0 = hp[0], q1 = hp[1], q2 = hp[2], q3 = hp[3];
    float hv[16] = {q0.x,q0.y,q0.z,q0.w, q1.x,q1.y,q1.z,q1.w,
                    q2.x,q2.y,q2.z,q2.w, q3.x,q3.y,q3.z,q3.w};
    #pragma unroll
    for (int k = 0; k < 16; ++k) {
      wlA[k] = fmaf(hv[k], w2a, wlA[k]);
      wlB[k] = fmaf(hv[k], w2b, wlB[k]);
    }
  }
  // phase C: softmax over k (per channel), weights reuse wlA/wlB
  {
    float mA = wlA[0], mB = wlB[0];
    #pragma unroll
    for (int k = 1; k < 16; ++k) { mA = fmaxf(mA, wlA[k]); mB = fmaxf(mB, wlB[k]); }
    float sA = 0.f, sB = 0.f;
    #pragma unroll
    for (int k = 0; k < 16; ++k) {
      wlA[k] = __expf(wlA[k] - mA); sA += wlA[k];
      wlB[k] = __expf(wlB[k] - mB); sB += wlB[k];
    }
    float rA = 1.0f/sA, rB = 1.0f/sB;
    #pragma unroll
    for (int k = 0; k < 16; ++k) { wlA[k] *= rA; wlB[k] *= rB; }
  }
  // phase D: hx[k][c] = lrelu(hxb[n] + Ad[m_k])
  {
    const float* Ad = ws + ADOFF;
    float hbA = ws[HXOFF + (size_t)n*Cc + t];
    float hbB = ws[HXOFF + (size_t)n*Cc + t + 64];
    #pragma unroll
    for (int k = 0; k < 16; ++k) {
      size_t mo = (size_t)mk[k]*Cc;
      float vA = hbA + Ad[mo + t];
      float vB = hbB + Ad[mo + t + 64];
      vA = (vA > 0.f ? vA : 0.2f*vA) * SQ2;
      vB = (vB > 0.f ? vB : 0.2f*vB) * SQ2;
      hx_s[t][k]      = vA;
      hx_s[t + 64][k] = vB;
    }
  }
  __syncthreads();
  // phase E: xe = hx @ Wx2 (+bx2), then agg = sum_k xe*wsm
  float xeA[16], xeB[16];
  #pragma unroll
  for (int k = 0; k < 16; ++k) { xeA[k] = 0.f; xeB[k] = 0.f; }
  for (int j = 0; j < 128; ++j) {
    float wxa = Wx2[j*FO + t];
    float wxb = Wx2[j*FO + t + 64];
    const float4* hp = (const float4*)(&hx_s[j][0]);
    float4 q0 = hp[0], q1 = hp[1], q2 = hp[2], q3 = hp[3];
    float hv[16] = {q0.x,q0.y,q0.z,q0.w, q1.x,q1.y,q1.z,q1.w,
                    q2.x,q2.y,q2.z,q2.w, q3.x,q3.y,q3.z,q3.w};
    #pragma unroll
    for (int k = 0; k < 16; ++k) {
      xeA[k] = fmaf(hv[k], wxa, xeA[k]);
      xeB[k] = fmaf(hv[k], wxb, xeB[k]);
    }
  }
  float bxa = bx2[t], bxb = bx2[t + 64];
  float aggA = 0.f, aggB = 0.f;
  #pragma unroll
  for (int k = 0; k < 16; ++k) {
    aggA = fmaf(xeA[k] + bxa, wlA[k], aggA);
    aggB = fmaf(xeB[k] + bxb, wlB[k], aggB);
  }
  float lsA = ws[LSOFF + b*Cc + t];
  float lsB = ws[LSOFF + b*Cc + t + 64];
  size_t xo = (size_t)n*Cc;
  out[xo + t]      = fmaf(aggA, lsA, x[xo + t]);
  out[xo + t + 64] = fmaf(aggB, lsB, x[xo + t + 64]);
}

// ---------------------------------------------------------------------------
extern "C" void kernel_launch(void* const* d_in, const int* in_sizes, int n_in,
                              void* d_out, int out_size, void* d_ws, size_t ws_size,
                              hipStream_t stream) {
  const float* x   = (const float*)d_in[0];
  const float* w   = (const float*)d_in[1];
  const float* Wg  = (const float*)d_in[2];
  const float* Wb  = (const float*)d_in[3];
  const float* W1  = (const float*)d_in[4];
  const float* b1  = (const float*)d_in[5];
  const float* W2  = (const float*)d_in[6];
  // d_in[7] = b2: unused (softmax over k is invariant to per-(n,c) shifts)
  const float* Wx1 = (const float*)d_in[8];
  const float* bx1 = (const float*)d_in[9];
  const float* Wx2 = (const float*)d_in[10];
  const float* bx2 = (const float*)d_in[11];
  const float* Wls = (const float*)d_in[12];
  const float* bls = (const float*)d_in[13];
  float* out = (float*)d_out;
  float* ws  = (float*)d_ws;

  k_pervec<<<Bz, Cc, 0, stream>>>(w, Wg, Wb, Wls, bls, ws);
  k_h<<<NP, 64, 0, stream>>>(x, ws);
  k_pre<<<NP/4, 128, 0, stream>>>(W1, Wx1, bx1, ws);
  k_knn<<<256, 256, 0, stream>>>(ws);
  k_mlp<<<NP, 64, 0, stream>>>(b1, W2, Wx2, bx2, x, out, ws);
}

// Round 2
// 602.719 us; speedup vs baseline: 1.1939x; 1.1939x over previous
//
#include <hip/hip_runtime.h>

#define Bz 8
#define Nn 2048
#define Cc 128
#define KK 16
#define WD 512
#define F2 64
#define FO 128
#define NP (Bz*Nn)
#define SQ2 1.41421356237309515f

// ws layout (float offsets)
#define GOFF   ((size_t)0)
#define BEOFF  ((size_t)1024)
#define LSOFF  ((size_t)2048)
#define HOFF   ((size_t)3072)
#define SQOFF  (HOFF + (size_t)NP*Cc)
#define A1OFF  (SQOFF + (size_t)NP)
#define ADOFF  (A1OFF + (size_t)NP*F2)
#define HXOFF  (ADOFF + (size_t)NP*Cc)
#define IXOFF  (HXOFF + (size_t)NP*Cc)
#define PDOFF  (IXOFF + (size_t)NP*KK)      // knn partial dists [np][2][17]
#define PIOFF  (PDOFF + (size_t)NP*34)      // knn partial ids   [np][2][17]

// ---------------------------------------------------------------------------
// Kernel 1: per-batch FiLM vectors. 512 thr: c=t&127, d-chunk=t>>7, LDS reduce.
__global__ __launch_bounds__(512) void k_pervec(const float* __restrict__ w,
    const float* __restrict__ Wg, const float* __restrict__ Wb,
    const float* __restrict__ Wls, const float* __restrict__ bls,
    float* __restrict__ ws) {
  __shared__ float red[3][4][Cc];
  const int b = blockIdx.x;
  const int c = threadIdx.x & 127, dc = threadIdx.x >> 7;
  const float* wr = w + b*WD;
  float ag = 0.f, ab = 0.f, al = 0.f;
  for (int d = dc*128; d < dc*128 + 128; ++d) {
    float wv = wr[d];
    ag = fmaf(wv, Wg[d*Cc + c], ag);
    ab = fmaf(wv, Wb[d*Cc + c], ab);
    al = fmaf(wv, Wls[d*Cc + c], al);
  }
  red[0][dc][c] = ag; red[1][dc][c] = ab; red[2][dc][c] = al;
  __syncthreads();
  if (dc == 0) {
    float sg = red[0][0][c] + red[0][1][c] + red[0][2][c] + red[0][3][c];
    float sb = red[1][0][c] + red[1][1][c] + red[1][2][c] + red[1][3][c];
    float sl = red[2][0][c] + red[2][1][c] + red[2][2][c] + red[2][3][c];
    ws[GOFF  + b*Cc + c] = 1.0f + sg;
    ws[BEOFF + b*Cc + c] = sb;
    ws[LSOFF + b*Cc + c] = sl + bls[c];
  }
}

// ---------------------------------------------------------------------------
// Kernel 2: h = LN(x)*g + beta, sq = sum(h*h).  One wave per row.
__global__ __launch_bounds__(64) void k_h(const float* __restrict__ x,
                                          float* __restrict__ ws) {
  const int n = blockIdx.x;
  const int b = n >> 11;
  const int t = threadIdx.x;
  const float* xr = x + (size_t)n*Cc;
  float x0 = xr[t], x1 = xr[t + 64];
  float s = x0 + x1, ss = x0*x0 + x1*x1;
  #pragma unroll
  for (int m = 1; m < 64; m <<= 1) {
    s  += __shfl_xor(s,  m, 64);
    ss += __shfl_xor(ss, m, 64);
  }
  float mu  = s * (1.0f/128.0f);
  float var = ss * (1.0f/128.0f) - mu*mu;
  float rs  = rsqrtf(var + 1e-5f);
  float h0 = (x0 - mu)*rs*ws[GOFF + b*Cc + t]      + ws[BEOFF + b*Cc + t];
  float h1 = (x1 - mu)*rs*ws[GOFF + b*Cc + t + 64] + ws[BEOFF + b*Cc + t + 64];
  float* hr = ws + HOFF + (size_t)n*Cc;
  hr[t] = h0; hr[t + 64] = h1;
  float q = h0*h0 + h1*h1;
  #pragma unroll
  for (int m = 1; m < 64; m <<= 1) q += __shfl_xor(q, m, 64);
  if (t == 0) ws[SQOFF + n] = q;
}

// ---------------------------------------------------------------------------
// Kernel 3: precompute A1 = h@W1, Ad = h@Wx1[128:], hxb = h@Wx1[:128]-Ad+bx1
__global__ __launch_bounds__(128) void k_pre(const float* __restrict__ W1,
    const float* __restrict__ Wx1, const float* __restrict__ bx1,
    float* __restrict__ ws) {
  __shared__ float hs[4][Cc];
  const int t = threadIdx.x;
  const size_t row0 = (size_t)blockIdx.x * 4;
  const float* h = ws + HOFF;
  #pragma unroll
  for (int r = 0; r < 4; ++r) hs[r][t] = h[(row0 + r)*Cc + t];
  __syncthreads();
  float ad[4] = {0,0,0,0}, ac[4] = {0,0,0,0};
  for (int cp = 0; cp < Cc; ++cp) {
    float whi = Wx1[cp*FO + t];
    float wlo = Wx1[(Cc + cp)*FO + t];
    #pragma unroll
    for (int r = 0; r < 4; ++r) {
      float hv = hs[r][cp];
      ac[r] = fmaf(hv, whi, ac[r]);
      ad[r] = fmaf(hv, wlo, ad[r]);
    }
  }
  float bx = bx1[t];
  #pragma unroll
  for (int r = 0; r < 4; ++r) {
    ws[ADOFF + (row0 + r)*Cc + t] = ad[r];
    ws[HXOFF + (row0 + r)*Cc + t] = ac[r] - ad[r] + bx;
  }
  const int j = t & 63, rp = t >> 6;
  float a0 = 0.f, a1 = 0.f;
  for (int cp = 0; cp < Cc; ++cp) {
    float wv = W1[cp*F2 + j];
    a0 = fmaf(hs[rp][cp],     wv, a0);
    a1 = fmaf(hs[rp + 2][cp], wv, a1);
  }
  ws[A1OFF + (row0 + rp)*F2 + j]     = a0;
  ws[A1OFF + (row0 + rp + 2)*F2 + j] = a1;
}

// ---------------------------------------------------------------------------
// top-17 insert, fully unrolled cndmask form (arrays stay in VGPRs)
__device__ __forceinline__ void ins17(float d, int id, float (&td)[17],
                                      int (&ti)[17], float& cmax, int& cpos) {
  #pragma unroll
  for (int s = 0; s < 17; ++s) {
    bool r = (s == cpos);
    td[s] = r ? d  : td[s];
    ti[s] = r ? id : ti[s];
  }
  cmax = td[0]; cpos = 0;
  #pragma unroll
  for (int s = 1; s < 17; ++s)
    if (td[s] > cmax) { cmax = td[s]; cpos = s; }
}

// ---------------------------------------------------------------------------
// Kernel 4: fused pairwise distance + partial kNN(17).
// grid 512: b(8) x i-tile(32, 64 rows) x j-chunk(2, 1024 cols). 256 thr.
// Thread tile 8x4 over a 64x128 (i x j) distance tile; j-tile loop of 8.
// LDS 53KB -> 2 blocks/CU resident = 8 waves/CU.
// sm[] aliases hB-staging [128][36] with dist-staging [64][67] (sync-fenced).
__global__ __launch_bounds__(256, 2) void k_knn(float* __restrict__ ws) {
  __shared__ float hA[64][132];   // i-tile, padded, b128-aligned rows
  __shared__ float sm[4608];      // union: hB[128][36] / dS[64][67] / merge [64][68]
  __shared__ float sqA[64];
  __shared__ float sqB[128];
  const int t   = threadIdx.x;
  const int blk = blockIdx.x;
  const int b   = blk >> 6;
  const int it  = (blk >> 1) & 31;
  const int jc  = blk & 1;
  const int i0  = it << 6;
  const int jbase = jc << 10;
  const float* __restrict__ h  = ws + HOFF  + (size_t)b*Nn*Cc;
  const float* __restrict__ sq = ws + SQOFF + (size_t)b*Nn;

  { // load hA: 64x128
    int r = t >> 2, cb = (t & 3) * 32;
    const float* src = h + (size_t)(i0 + r)*Cc + cb;
    #pragma unroll
    for (int q = 0; q < 8; ++q)
      *(float4*)(&hA[r][cb + q*4]) = *(const float4*)(src + q*4);
  }
  if (t < 64) sqA[t] = sq[i0 + t];

  const int tx = t & 31, ty = t >> 5;     // j-group (cols tx+32d), i-group (rows ty+8a)
  const int iown = t & 63, qd = t >> 6;   // selection ownership

  float td[17]; int ti[17];
  #pragma unroll
  for (int s = 0; s < 17; ++s) { td[s] = 3.0e38f; ti[s] = -1; }
  float cmax = 3.0e38f; int cpos = 0;

  for (int jt = 0; jt < 8; ++jt) {
    const int j0 = jbase + jt*128;
    if (t < 128) sqB[t] = sq[j0 + t];
    float acc[8][4];
    #pragma unroll
    for (int a = 0; a < 8; ++a)
      #pragma unroll
      for (int d = 0; d < 4; ++d) acc[a][d] = 0.f;

    for (int cc = 0; cc < 4; ++cc) {
      __syncthreads();               // prev use of sm done (select / prev chunk FMA)
      { // load hB chunk: 128 j-rows x 32 cols
        int r = t >> 1, cb = (t & 1) * 16;
        const float* src = h + (size_t)(j0 + r)*Cc + cc*32 + cb;
        float* dst = &sm[r*36 + cb];
        #pragma unroll
        for (int q = 0; q < 4; ++q)
          *(float4*)(dst + q*4) = *(const float4*)(src + q*4);
      }
      __syncthreads();
      #pragma unroll
      for (int q = 0; q < 8; ++q) {
        float4 av[8], bv[4];
        #pragma unroll
        for (int a = 0; a < 8; ++a)
          av[a] = *(const float4*)(&hA[ty + 8*a][cc*32 + q*4]);
        #pragma unroll
        for (int d = 0; d < 4; ++d)
          bv[d] = *(const float4*)(&sm[(tx + 32*d)*36 + q*4]);
        #pragma unroll
        for (int a = 0; a < 8; ++a)
          #pragma unroll
          for (int d = 0; d < 4; ++d) {
            acc[a][d] = fmaf(av[a].x, bv[d].x, acc[a][d]);
            acc[a][d] = fmaf(av[a].y, bv[d].y, acc[a][d]);
            acc[a][d] = fmaf(av[a].z, bv[d].z, acc[a][d]);
            acc[a][d] = fmaf(av[a].w, bv[d].w, acc[a][d]);
          }
      }
    }
    // two half-tiles of 64 cols: stage dists into sm (stride 67 -> 2-way, free)
    #pragma unroll
    for (int half = 0; half < 2; ++half) {
      __syncthreads();               // FMA reads of sm done / prev select done
      #pragma unroll
      for (int a = 0; a < 8; ++a)
        #pragma unroll
        for (int dd = 0; dd < 2; ++dd) {
          int d = half*2 + dd;
          sm[(ty + 8*a)*67 + tx + 32*dd] =
              sqA[ty + 8*a] + sqB[64*half + tx + 32*dd] - 2.f*acc[a][d];
        }
      __syncthreads();
      const int joff = j0 + 64*half;
      #pragma unroll 1
      for (int jj = 0; jj < 16; ++jj) {
        int c = qd*16 + jj;
        float dv = sm[iown*67 + c];
        if (dv < cmax) ins17(dv, joff + c, td, ti, cmax, cpos);
      }
    }
  }
  __syncthreads();
  // dump 4 partial lists per row (ids bit-cast into hA, now dead)
  #pragma unroll
  for (int s = 0; s < 17; ++s) {
    sm[iown*68 + qd*17 + s] = td[s];
    ((float*)hA)[iown*132 + qd*17 + s] = __int_as_float(ti[s]);
  }
  __syncthreads();
  if (t < 64) {
    float md[17]; int mi[17];
    #pragma unroll
    for (int s = 0; s < 17; ++s) { md[s] = 3.0e38f; mi[s] = -1; }
    float cm = 3.0e38f; int cp = 0;
    for (int s = 0; s < 68; ++s) {
      float dv = sm[t*68 + s];
      int  id  = __float_as_int(((float*)hA)[t*132 + s]);
      if (dv < cm) ins17(dv, id, md, mi, cm, cp);
    }
    const size_t row = (size_t)(b*Nn + i0 + t);
    float* pd = ws + PDOFF + row*34 + jc*17;
    int*   pi = (int*)(ws + PIOFF) + row*34 + jc*17;
    #pragma unroll
    for (int s = 0; s < 17; ++s) { pd[s] = md[s]; pi[s] = mi[s]; }
  }
}

// ---------------------------------------------------------------------------
// Kernel 4b: merge the 2 per-chunk top-17 lists -> top-17 -> drop self -> idx
__global__ __launch_bounds__(64) void k_kmerge(float* __restrict__ ws) {
  const int row = blockIdx.x*64 + threadIdx.x;
  const int b = row >> 11;
  const float* pd = ws + PDOFF + (size_t)row*34;
  const int*   pi = (const int*)(ws + PIOFF) + (size_t)row*34;
  float md[17]; int mi[17];
  #pragma unroll
  for (int s = 0; s < 17; ++s) { md[s] = 3.0e38f; mi[s] = -1; }
  float cm = 3.0e38f; int cp = 0;
  for (int s = 0; s < 34; ++s) {
    float dv = pd[s];
    if (dv < cm) ins17(dv, pi[s], md, mi, cm, cp);
  }
  float mn = md[0]; int mp = 0;                // drop closest (= self)
  #pragma unroll
  for (int s = 1; s < 17; ++s) if (md[s] < mn) { mn = md[s]; mp = s; }
  int* op = (int*)(ws + IXOFF) + (size_t)row*KK;
  int kk = 0;
  #pragma unroll
  for (int s = 0; s < 17; ++s)
    if (s != mp) op[kk++] = b*Nn + mi[s];
}

// ---------------------------------------------------------------------------
// Kernel 5: fused per-point MLP + softmax + aggregate + residual.
// b2 omitted: constant over k -> cancels in softmax (exact).
__global__ __launch_bounds__(64) void k_mlp(
    const float* __restrict__ b1v, const float* __restrict__ W2,
    const float* __restrict__ Wx2, const float* __restrict__ bx2,
    const float* __restrict__ x, float* __restrict__ out,
    float* __restrict__ ws) {
  __shared__ float hw_s[64][20];
  __shared__ float hx_s[128][20];
  __shared__ int mk[16];
  const int n = blockIdx.x;
  const int b = n >> 11;
  const int t = threadIdx.x;
  const int* __restrict__ ip = (const int*)(ws + IXOFF) + (size_t)n*KK;
  if (t < 16) mk[t] = ip[t];
  __syncthreads();
  {
    const float* A1 = ws + A1OFF;
    float a1n = A1[(size_t)n*F2 + t];
    float bb  = b1v[t];
    #pragma unroll
    for (int k = 0; k < 16; ++k) {
      float v = A1[(size_t)mk[k]*F2 + t] - a1n + bb;
      v = (v > 0.f ? v : 0.2f*v) * SQ2;
      hw_s[t][k] = v;
    }
  }
  __syncthreads();
  float wlA[16], wlB[16];
  #pragma unroll
  for (int k = 0; k < 16; ++k) { wlA[k] = 0.f; wlB[k] = 0.f; }
  for (int j = 0; j < 64; ++j) {
    float w2a = W2[j*FO + t];
    float w2b = W2[j*FO + t + 64];
    const float4* hp = (const float4*)(&hw_s[j][0]);
    float4 q0 = hp[0], q1 = hp[1], q2 = hp[2], q3 = hp[3];
    float hv[16] = {q0.x,q0.y,q0.z,q0.w, q1.x,q1.y,q1.z,q1.w,
                    q2.x,q2.y,q2.z,q2.w, q3.x,q3.y,q3.z,q3.w};
    #pragma unroll
    for (int k = 0; k < 16; ++k) {
      wlA[k] = fmaf(hv[k], w2a, wlA[k]);
      wlB[k] = fmaf(hv[k], w2b, wlB[k]);
    }
  }
  {
    float mA = wlA[0], mB = wlB[0];
    #pragma unroll
    for (int k = 1; k < 16; ++k) { mA = fmaxf(mA, wlA[k]); mB = fmaxf(mB, wlB[k]); }
    float sA = 0.f, sB = 0.f;
    #pragma unroll
    for (int k = 0; k < 16; ++k) {
      wlA[k] = __expf(wlA[k] - mA); sA += wlA[k];
      wlB[k] = __expf(wlB[k] - mB); sB += wlB[k];
    }
    float rA = 1.0f/sA, rB = 1.0f/sB;
    #pragma unroll
    for (int k = 0; k < 16; ++k) { wlA[k] *= rA; wlB[k] *= rB; }
  }
  {
    const float* Ad = ws + ADOFF;
    float hbA = ws[HXOFF + (size_t)n*Cc + t];
    float hbB = ws[HXOFF + (size_t)n*Cc + t + 64];
    #pragma unroll
    for (int k = 0; k < 16; ++k) {
      size_t mo = (size_t)mk[k]*Cc;
      float vA = hbA + Ad[mo + t];
      float vB = hbB + Ad[mo + t + 64];
      vA = (vA > 0.f ? vA : 0.2f*vA) * SQ2;
      vB = (vB > 0.f ? vB : 0.2f*vB) * SQ2;
      hx_s[t][k]      = vA;
      hx_s[t + 64][k] = vB;
    }
  }
  __syncthreads();
  float xeA[16], xeB[16];
  #pragma unroll
  for (int k = 0; k < 16; ++k) { xeA[k] = 0.f; xeB[k] = 0.f; }
  for (int j = 0; j < 128; ++j) {
    float wxa = Wx2[j*FO + t];
    float wxb = Wx2[j*FO + t + 64];
    const float4* hp = (const float4*)(&hx_s[j][0]);
    float4 q0 = hp[0], q1 = hp[1], q2 = hp[2], q3 = hp[3];
    float hv[16] = {q0.x,q0.y,q0.z,q0.w, q1.x,q1.y,q1.z,q1.w,
                    q2.x,q2.y,q2.z,q2.w, q3.x,q3.y,q3.z,q3.w};
    #pragma unroll
    for (int k = 0; k < 16; ++k) {
      xeA[k] = fmaf(hv[k], wxa, xeA[k]);
      xeB[k] = fmaf(hv[k], wxb, xeB[k]);
    }
  }
  float bxa = bx2[t], bxb = bx2[t + 64];
  float aggA = 0.f, aggB = 0.f;
  #pragma unroll
  for (int k = 0; k < 16; ++k) {
    aggA = fmaf(xeA[k] + bxa, wlA[k], aggA);
    aggB = fmaf(xeB[k] + bxb, wlB[k], aggB);
  }
  float lsA = ws[LSOFF + b*Cc + t];
  float lsB = ws[LSOFF + b*Cc + t + 64];
  size_t xo = (size_t)n*Cc;
  out[xo + t]      = fmaf(aggA, lsA, x[xo + t]);
  out[xo + t + 64] = fmaf(aggB, lsB, x[xo + t + 64]);
}

// ---------------------------------------------------------------------------
extern "C" void kernel_launch(void* const* d_in, const int* in_sizes, int n_in,
                              void* d_out, int out_size, void* d_ws, size_t ws_size,
                              hipStream_t stream) {
  const float* x   = (const float*)d_in[0];
  const float* w   = (const float*)d_in[1];
  const float* Wg  = (const float*)d_in[2];
  const float* Wb  = (const float*)d_in[3];
  const float* W1  = (const float*)d_in[4];
  const float* b1  = (const float*)d_in[5];
  const float* W2  = (const float*)d_in[6];
  const float* Wx1 = (const float*)d_in[8];
  const float* bx1 = (const float*)d_in[9];
  const float* Wx2 = (const float*)d_in[10];
  const float* bx2 = (const float*)d_in[11];
  const float* Wls = (const float*)d_in[12];
  const float* bls = (const float*)d_in[13];
  float* out = (float*)d_out;
  float* ws  = (float*)d_ws;

  k_pervec<<<Bz, 512, 0, stream>>>(w, Wg, Wb, Wls, bls, ws);
  k_h<<<NP, 64, 0, stream>>>(x, ws);
  k_pre<<<NP/4, 128, 0, stream>>>(W1, Wx1, bx1, ws);
  k_knn<<<512, 256, 0, stream>>>(ws);
  k_kmerge<<<NP/64, 64, 0, stream>>>(ws);
  k_mlp<<<NP, 64, 0, stream>>>(b1, W2, Wx2, bx2, x, out, ws);
}